// Round 7
// baseline (192.160 us; speedup 1.0000x reference)
//
#include <hip/hip_runtime.h>

#define NB    64
#define IN    512
#define OUT   512
#define NTOK  512       // B*T
#define NSEL  1024      // NTOK*K
#define TCAP  32        // token slots per pass
#define XSTR  260       // xs float stride per slot (260%32=4 -> bank spread)
#define ELCAP 96        // per-bank list cap (mean 16, sd ~4; 96 = +20 sigma)

// Block = (bank, 64-col tile, 256-row half). 256 threads, 4 waves:
//   wave w = 64-row slice; lane: ct = l&15 (float4 col), g = l>>4 (token
//   subgroup -> W addr independent of g: 4-way in-wave dup, coalesced).
// Thread: acc over 8 token slots (4j+g) x 4 cols; W fragment read once,
// software-pipelined (ping-pong prefetch of next 4-row chunk).
// Cross-wave reduce: plain stores to red (aliases xs), readback. No atomics.
__global__ __launch_bounds__(256) void banked_gemv(
    const float* __restrict__ x,      // [NTOK][IN]
    const int*   __restrict__ sel,    // [NSEL]
    const float* __restrict__ probs,  // [NSEL]
    const float* __restrict__ W,      // [NB][IN][OUT]
    const float* __restrict__ bias,   // [NB][OUT]
    float* __restrict__ ysel)         // [NSEL][2][OUT]
{
    __shared__ __align__(16) float xs[TCAP * XSTR];   // 33.3 KB; red aliases 32 KB
    __shared__ int   elist[ELCAP];
    __shared__ int   lcnt;
    __shared__ int   tok_s[TCAP];
    __shared__ float prob_s[TCAP];

    const int bank = blockIdx.x >> 4;
    const int tile = (blockIdx.x >> 1) & 7;
    const int half = blockIdx.x & 1;
    const int t    = threadIdx.x;

    // build this bank's selection list (slot order free; math slot-invariant)
    if (t == 0) lcnt = 0;
    __syncthreads();
    {
        const int4 s4 = reinterpret_cast<const int4*>(sel)[t];
        if (s4.x == bank) { const int p = atomicAdd(&lcnt, 1); if (p < ELCAP) elist[p] = 4 * t; }
        if (s4.y == bank) { const int p = atomicAdd(&lcnt, 1); if (p < ELCAP) elist[p] = 4 * t + 1; }
        if (s4.z == bank) { const int p = atomicAdd(&lcnt, 1); if (p < ELCAP) elist[p] = 4 * t + 2; }
        if (s4.w == bank) { const int p = atomicAdd(&lcnt, 1); if (p < ELCAP) elist[p] = 4 * t + 3; }
    }
    __syncthreads();
    const int n = min(lcnt, ELCAP);
    if (n == 0) return;

    const int l  = t & 63;
    const int w  = t >> 6;      // wave = 64-row slice
    const int ct = l & 15;      // float4 col within 64-col tile
    const int g  = l >> 4;      // token subgroup 0..3
    const int col0 = tile * 64;
    const int row0 = half * 256 + w * 64;
    const float* wbase = W + (size_t)bank * (IN * OUT) + (size_t)row0 * OUT + col0 + ct * 4;

#define LD4(p) (*reinterpret_cast<const float4*>(p))
#define FMA_CHUNK(W0, W1, W2, W3, CHK)                                          \
    {                                                                           \
        _Pragma("unroll")                                                       \
        for (int j = 0; j < 8; ++j) {                                           \
            const float4 xv = LD4(xb + (4 * j + g) * XSTR + (CHK) * 4);         \
            acc[j].x += xv.x * W0.x + xv.y * W1.x + xv.z * W2.x + xv.w * W3.x;  \
            acc[j].y += xv.x * W0.y + xv.y * W1.y + xv.z * W2.y + xv.w * W3.y;  \
            acc[j].z += xv.x * W0.z + xv.y * W1.z + xv.z * W2.z + xv.w * W3.z;  \
            acc[j].w += xv.x * W0.w + xv.y * W1.w + xv.z * W2.w + xv.w * W3.w;  \
        }                                                                       \
    }

    for (int c0 = 0; c0 < n; c0 += TCAP) {
        if (t < TCAP) {
            const int idx = c0 + t;
            const int e = (idx < n) ? elist[idx] : -1;
            tok_s[t]  = (e >= 0) ? (e >> 1) : 0;
            prob_s[t] = (e >= 0) ? probs[e] : 0.0f;
        }
        __syncthreads();

        // stage xs pre-scaled: 32 slots x 64 float4 (this half's rows); 8/thread
        #pragma unroll
        for (int k2 = 0; k2 < 8; ++k2) {
            const int oid  = t + k2 * 256;
            const int slot = oid >> 6;
            const int c4   = oid & 63;
            float4 v = LD4(x + (size_t)tok_s[slot] * IN + half * 256 + c4 * 4);
            const float p = prob_s[slot];
            v.x *= p; v.y *= p; v.z *= p; v.w *= p;
            *reinterpret_cast<float4*>(xs + slot * XSTR + c4 * 4) = v;
        }
        __syncthreads();

        float4 acc[8];
        #pragma unroll
        for (int j = 0; j < 8; ++j) acc[j] = make_float4(0.f, 0.f, 0.f, 0.f);

        const float* xb = xs + w * 64;
        // software-pipelined weight stream: ping-pong wa/wb, prefetch chunk+1
        float4 wa0, wa1, wa2, wa3, wb0, wb1, wb2, wb3;
        {
            const float* wr = wbase;
            wa0 = LD4(wr); wa1 = LD4(wr + OUT); wa2 = LD4(wr + 2 * OUT); wa3 = LD4(wr + 3 * OUT);
        }
        #pragma unroll
        for (int cp = 0; cp < 8; ++cp) {
            {   // even chunk 2cp: prefetch 2cp+1, compute with wa
                const float* wr = wbase + (size_t)((2 * cp + 1) * 4) * OUT;
                wb0 = LD4(wr); wb1 = LD4(wr + OUT); wb2 = LD4(wr + 2 * OUT); wb3 = LD4(wr + 3 * OUT);
                FMA_CHUNK(wa0, wa1, wa2, wa3, 2 * cp);
            }
            {   // odd chunk 2cp+1: prefetch 2cp+2 (if any), compute with wb
                if (cp < 7) {
                    const float* wr = wbase + (size_t)((2 * cp + 2) * 4) * OUT;
                    wa0 = LD4(wr); wa1 = LD4(wr + OUT); wa2 = LD4(wr + 2 * OUT); wa3 = LD4(wr + 3 * OUT);
                }
                FMA_CHUNK(wb0, wb1, wb2, wb3, 2 * cp + 1);
            }
        }
        __syncthreads();   // xs consumed; reuse as red

        float4* red = reinterpret_cast<float4*>(xs);   // [w][slot][ct] = 32 KB
        #pragma unroll
        for (int j = 0; j < 8; ++j)
            red[w * (TCAP * 16) + (4 * j + g) * 16 + ct] = acc[j];
        __syncthreads();

        // final cross-wave reduce + store: 512 outputs, 2/thread
        #pragma unroll
        for (int k2 = 0; k2 < 2; ++k2) {
            const int oid  = t + k2 * 256;
            const int slot = oid >> 4;
            const int c    = oid & 15;
            if (c0 + slot < n) {
                const float4 a0 = red[0 * 512 + slot * 16 + c];
                const float4 a1 = red[1 * 512 + slot * 16 + c];
                const float4 a2 = red[2 * 512 + slot * 16 + c];
                const float4 a3 = red[3 * 512 + slot * 16 + c];
                float4 sum;
                sum.x = (a0.x + a1.x) + (a2.x + a3.x);
                sum.y = (a0.y + a1.y) + (a2.y + a3.y);
                sum.z = (a0.z + a1.z) + (a2.z + a3.z);
                sum.w = (a0.w + a1.w) + (a2.w + a3.w);
                if (half == 0) {
                    const float p = prob_s[slot];
                    const float4 bv = LD4(bias + bank * OUT + col0 + c * 4);
                    sum.x += p * bv.x; sum.y += p * bv.y;
                    sum.z += p * bv.z; sum.w += p * bv.w;
                }
                const int e = elist[c0 + slot];
                *reinterpret_cast<float4*>(
                    ysel + ((size_t)e * 2 + half) * OUT + col0 + c * 4) = sum;
            }
        }
        __syncthreads();   // before restaging xs next pass
    }
#undef FMA_CHUNK
#undef LD4
}

// out[t] = sum over (k=2 selections) x (2 halves)
__global__ __launch_bounds__(256) void combine(const float* __restrict__ ysel,
                                               float* __restrict__ out) {
    const int i  = blockIdx.x * 256 + threadIdx.x;   // float4 index, 65536
    const int tk = i >> 7;
    const int c  = i & 127;
    const float4* y4 = reinterpret_cast<const float4*>(ysel);
    const size_t b0 = (size_t)(2 * tk) * 2 * 128;    // [e][half][128 f4]
    const float4 a  = y4[b0 + c];
    const float4 b  = y4[b0 + 128 + c];
    const float4 cc = y4[b0 + 256 + c];
    const float4 d  = y4[b0 + 384 + c];
    float4 r;
    r.x = (a.x + b.x) + (cc.x + d.x);
    r.y = (a.y + b.y) + (cc.y + d.y);
    r.z = (a.z + b.z) + (cc.z + d.z);
    r.w = (a.w + b.w) + (cc.w + d.w);
    reinterpret_cast<float4*>(out)[i] = r;
}

extern "C" void kernel_launch(void* const* d_in, const int* in_sizes, int n_in,
                              void* d_out, int out_size, void* d_ws, size_t ws_size,
                              hipStream_t stream) {
    const float* x     = (const float*)d_in[0];
    const int*   sel   = (const int*)d_in[1];
    const float* probs = (const float*)d_in[2];
    const float* W     = (const float*)d_in[3];
    const float* bias  = (const float*)d_in[4];
    float* out  = (float*)d_out;
    float* ysel = (float*)d_ws;     // [NSEL][2][OUT] = 4 MB

    banked_gemv<<<NB * 8 * 2, 256, 0, stream>>>(x, sel, probs, W, bias, ysel);
    combine<<<(NTOK * OUT / 4) / 256, 256, 0, stream>>>(ysel, out);
}

// Round 8
// 28.177 us; speedup vs baseline: 6.8198x; 6.8198x over previous
//
#include <hip/hip_runtime.h>

#define NB    64
#define IN    512
#define OUT   512
#define NTOK  512       // B*T
#define NSEL  1024      // NTOK*K
#define TCAP  16        // token slots per pass
#define XSTR  260       // xs float stride per slot (260%32=4 -> bank spread)
#define ELCAP 96        // per-bank list cap (mean 16, sd ~4)

// Block = (bank, 64-col tile, 256-row half). 256 threads, 4 waves:
//   wave w = 64-row slice; lane: ct = l&15 (float4 col), g = l>>4 (token
//   subgroup -> W addr independent of g: 4-way in-wave dup, coalesced).
// Thread: acc over 4 token slots (4j+g) x 4 cols; W fragment read once per
// pass, compiler-scheduled loads (no manual prefetch -- R7 spill lesson).
// Cross-wave reduce: plain stores to red (aliases xs), readback. No atomics.
__global__ __launch_bounds__(256) void banked_gemv(
    const float* __restrict__ x,      // [NTOK][IN]
    const int*   __restrict__ sel,    // [NSEL]
    const float* __restrict__ probs,  // [NSEL]
    const float* __restrict__ W,      // [NB][IN][OUT]
    const float* __restrict__ bias,   // [NB][OUT]
    float* __restrict__ ysel)         // [NSEL][2][OUT]
{
    __shared__ __align__(16) float xs[TCAP * XSTR];   // 16.6 KB; red aliases 16 KB
    __shared__ int   elist[ELCAP];
    __shared__ int   lcnt;
    __shared__ int   tok_s[TCAP];
    __shared__ float prob_s[TCAP];

    const int bank = blockIdx.x >> 4;
    const int tile = (blockIdx.x >> 1) & 7;
    const int half = blockIdx.x & 1;
    const int t    = threadIdx.x;

    // build this bank's selection list (slot order free; math slot-invariant)
    if (t == 0) lcnt = 0;
    __syncthreads();
    {
        const int4 s4 = reinterpret_cast<const int4*>(sel)[t];
        if (s4.x == bank) { const int p = atomicAdd(&lcnt, 1); if (p < ELCAP) elist[p] = 4 * t; }
        if (s4.y == bank) { const int p = atomicAdd(&lcnt, 1); if (p < ELCAP) elist[p] = 4 * t + 1; }
        if (s4.z == bank) { const int p = atomicAdd(&lcnt, 1); if (p < ELCAP) elist[p] = 4 * t + 2; }
        if (s4.w == bank) { const int p = atomicAdd(&lcnt, 1); if (p < ELCAP) elist[p] = 4 * t + 3; }
    }
    __syncthreads();
    const int n = min(lcnt, ELCAP);
    if (n == 0) return;

    const int l  = t & 63;
    const int w  = t >> 6;      // wave = 64-row slice
    const int ct = l & 15;      // float4 col within 64-col tile
    const int g  = l >> 4;      // token subgroup 0..3
    const int col0 = tile * 64;
    const int row0 = half * 256 + w * 64;
    const float* wbase = W + (size_t)bank * (IN * OUT) + (size_t)row0 * OUT + col0 + ct * 4;

    for (int c0 = 0; c0 < n; c0 += TCAP) {
        if (t < TCAP) {
            const int idx = c0 + t;
            const int e = (idx < n) ? elist[idx] : -1;
            tok_s[t]  = (e >= 0) ? (e >> 1) : 0;
            prob_s[t] = (e >= 0) ? probs[e] : 0.0f;
        }
        __syncthreads();

        // stage xs pre-scaled: 16 slots x 64 float4 (this half's rows); 4/thread
        #pragma unroll
        for (int k2 = 0; k2 < 4; ++k2) {
            const int oid  = t + k2 * 256;
            const int slot = oid >> 6;
            const int c4   = oid & 63;
            float4 v = *reinterpret_cast<const float4*>(
                x + (size_t)tok_s[slot] * IN + half * 256 + c4 * 4);
            const float p = prob_s[slot];
            v.x *= p; v.y *= p; v.z *= p; v.w *= p;
            *reinterpret_cast<float4*>(xs + slot * XSTR + c4 * 4) = v;
        }
        __syncthreads();

        float4 acc[4];
        #pragma unroll
        for (int j = 0; j < 4; ++j) acc[j] = make_float4(0.f, 0.f, 0.f, 0.f);

        const float* xb = xs + w * 64;
        #pragma unroll 2
        for (int chunk = 0; chunk < 16; ++chunk) {
            const float* wr = wbase + (size_t)(chunk * 4) * OUT;
            const float4 w0 = *reinterpret_cast<const float4*>(wr);
            const float4 w1 = *reinterpret_cast<const float4*>(wr + OUT);
            const float4 w2 = *reinterpret_cast<const float4*>(wr + 2 * OUT);
            const float4 w3 = *reinterpret_cast<const float4*>(wr + 3 * OUT);
            #pragma unroll
            for (int j = 0; j < 4; ++j) {
                const float4 xv = *reinterpret_cast<const float4*>(
                    xb + (4 * j + g) * XSTR + chunk * 4);
                acc[j].x += xv.x * w0.x + xv.y * w1.x + xv.z * w2.x + xv.w * w3.x;
                acc[j].y += xv.x * w0.y + xv.y * w1.y + xv.z * w2.y + xv.w * w3.y;
                acc[j].z += xv.x * w0.z + xv.y * w1.z + xv.z * w2.z + xv.w * w3.z;
                acc[j].w += xv.x * w0.w + xv.y * w1.w + xv.z * w2.w + xv.w * w3.w;
            }
        }
        __syncthreads();   // xs consumed; reuse as red

        float4* red = reinterpret_cast<float4*>(xs);   // [w][slot][ct] = 16 KB
        #pragma unroll
        for (int j = 0; j < 4; ++j)
            red[w * (TCAP * 16) + (4 * j + g) * 16 + ct] = acc[j];
        __syncthreads();

        // final cross-wave reduce + store: 256 outputs, 1/thread
        {
            const int slot = t >> 4;
            const int c    = t & 15;
            if (c0 + slot < n) {
                const float4 a0 = red[0 * 256 + slot * 16 + c];
                const float4 a1 = red[1 * 256 + slot * 16 + c];
                const float4 a2 = red[2 * 256 + slot * 16 + c];
                const float4 a3 = red[3 * 256 + slot * 16 + c];
                float4 sum;
                sum.x = (a0.x + a1.x) + (a2.x + a3.x);
                sum.y = (a0.y + a1.y) + (a2.y + a3.y);
                sum.z = (a0.z + a1.z) + (a2.z + a3.z);
                sum.w = (a0.w + a1.w) + (a2.w + a3.w);
                if (half == 0) {
                    const float p = prob_s[slot];
                    const float4 bv = *reinterpret_cast<const float4*>(
                        bias + bank * OUT + col0 + c * 4);
                    sum.x += p * bv.x; sum.y += p * bv.y;
                    sum.z += p * bv.z; sum.w += p * bv.w;
                }
                const int e = elist[c0 + slot];
                *reinterpret_cast<float4*>(
                    ysel + ((size_t)e * 2 + half) * OUT + col0 + c * 4) = sum;
            }
        }
        __syncthreads();   // before restaging xs next pass
    }
}

// out[t] = sum over (k=2 selections) x (2 halves)
__global__ __launch_bounds__(256) void combine(const float* __restrict__ ysel,
                                               float* __restrict__ out) {
    const int i  = blockIdx.x * 256 + threadIdx.x;   // float4 index, 65536
    const int tk = i >> 7;
    const int c  = i & 127;
    const float4* y4 = reinterpret_cast<const float4*>(ysel);
    const size_t b0 = (size_t)(2 * tk) * 2 * 128;    // [e][half][128 f4]
    const float4 a  = y4[b0 + c];
    const float4 b  = y4[b0 + 128 + c];
    const float4 cc = y4[b0 + 256 + c];
    const float4 d  = y4[b0 + 384 + c];
    float4 r;
    r.x = (a.x + b.x) + (cc.x + d.x);
    r.y = (a.y + b.y) + (cc.y + d.y);
    r.z = (a.z + b.z) + (cc.z + d.z);
    r.w = (a.w + b.w) + (cc.w + d.w);
    reinterpret_cast<float4*>(out)[i] = r;
}

extern "C" void kernel_launch(void* const* d_in, const int* in_sizes, int n_in,
                              void* d_out, int out_size, void* d_ws, size_t ws_size,
                              hipStream_t stream) {
    const float* x     = (const float*)d_in[0];
    const int*   sel   = (const int*)d_in[1];
    const float* probs = (const float*)d_in[2];
    const float* W     = (const float*)d_in[3];
    const float* bias  = (const float*)d_in[4];
    float* out  = (float*)d_out;
    float* ysel = (float*)d_ws;     // [NSEL][2][OUT] = 4 MB

    banked_gemv<<<NB * 8 * 2, 256, 0, stream>>>(x, sel, probs, W, bias, ysel);
    combine<<<(NTOK * OUT / 4) / 256, 256, 0, stream>>>(ysel, out);
}

// Round 9
// 23.400 us; speedup vs baseline: 8.2118x; 1.2041x over previous
//
#include <hip/hip_runtime.h>
#include <stdint.h>

#define NB    64
#define IN    512
#define OUT   512
#define NTOK  512
#define NSEL  1024      // NTOK*K
#define MCAP  32        // token slots per pass (binomial mean 16, sd 4 -> 1 pass)
#define XSTR  520       // bf16 per X row (512 + 8 pad; dword-stride%32==4 -> 2-way)
#define ELCAP 96

typedef __attribute__((ext_vector_type(8))) short bf16x8;
typedef __attribute__((ext_vector_type(4))) float f32x4;

__device__ __forceinline__ ushort f2bf(float f) {   // RNE f32->bf16
    uint32_t u = __builtin_bit_cast(uint32_t, f);
    u += 0x7fffu + ((u >> 16) & 1u);
    return (ushort)(u >> 16);
}

// Block = (bank, 128-col tile): 256 blocks, 512 threads = 8 waves.
// Wave w = N-tile of 16 cols. Per pass: <=32 tokens, mt<=2 M-tiles of 16.
// A (X) staged in LDS bf16, read as fragments (m89-verified layouts:
//   A: row=lane&15, k=(lane>>4)*8+i ; B: col=lane&15, same k ;
//   D: col=lane&15, row=(lane>>4)*4+reg).
// B (W) loaded straight from global per-lane (no LDS transpose), bf16-packed.
// K-loop is barrier-free. Epilogue: ysel[e][col] = p*(acc + bias).
__global__ __launch_bounds__(512) void banked_mfma(
    const float* __restrict__ x,      // [NTOK][IN]
    const int*   __restrict__ sel,    // [NSEL]
    const float* __restrict__ probs,  // [NSEL]
    const float* __restrict__ W,      // [NB][IN][OUT]
    const float* __restrict__ bias,   // [NB][OUT]
    float* __restrict__ ysel)         // [NSEL][OUT]
{
    __shared__ __align__(16) ushort Xs[MCAP * XSTR];   // 33.3 KB
    __shared__ int   elist[ELCAP];
    __shared__ int   lcnt;
    __shared__ int   tok_s[MCAP];
    __shared__ float prob_s[MCAP];

    const int bank = blockIdx.x >> 2;
    const int ct   = blockIdx.x & 3;       // 128-col tile
    const int t    = threadIdx.x;

    // fused per-bank selection list (slot order free; per-e math invariant)
    if (t == 0) lcnt = 0;
    __syncthreads();
    if (t < NSEL / 4) {
        const int4 s4 = reinterpret_cast<const int4*>(sel)[t];
        if (s4.x == bank) { int p = atomicAdd(&lcnt, 1); if (p < ELCAP) elist[p] = 4 * t; }
        if (s4.y == bank) { int p = atomicAdd(&lcnt, 1); if (p < ELCAP) elist[p] = 4 * t + 1; }
        if (s4.z == bank) { int p = atomicAdd(&lcnt, 1); if (p < ELCAP) elist[p] = 4 * t + 2; }
        if (s4.w == bank) { int p = atomicAdd(&lcnt, 1); if (p < ELCAP) elist[p] = 4 * t + 3; }
    }
    __syncthreads();
    const int n = min(lcnt, ELCAP);
    if (n == 0) return;

    const int w   = t >> 6;        // wave = N-tile 0..7
    const int l   = t & 63;
    const int g   = l >> 4;        // lane group 0..3
    const int ln  = l & 15;
    const int col = ct * 128 + w * 16 + ln;
    const float* wcol = W + (size_t)bank * (IN * OUT) + col;   // + k*OUT
    const float  bcol = bias[bank * OUT + col];

    for (int c0 = 0; c0 < n; c0 += MCAP) {
        const int n_c    = min(n - c0, MCAP);
        const int mt_cnt = (n_c + 15) >> 4;

        if (t < MCAP) {
            const int idx = c0 + t;
            const int e = (idx < n) ? elist[idx] : 0;
            tok_s[t]  = e >> 1;
            prob_s[t] = (idx < n) ? probs[e] : 0.0f;
        }
        __syncthreads();

        // stage X -> LDS bf16: slot = t>>4, 8 float4 per thread
        {
            const int slot = t >> 4;
            const float* xrow = x + (size_t)tok_s[slot] * IN;
            #pragma unroll
            for (int r = 0; r < 8; ++r) {
                const int f4 = (t & 15) + 16 * r;
                const float4 v = reinterpret_cast<const float4*>(xrow)[f4];
                ushort4 b;
                b.x = f2bf(v.x); b.y = f2bf(v.y); b.z = f2bf(v.z); b.w = f2bf(v.w);
                *reinterpret_cast<ushort4*>(&Xs[slot * XSTR + f4 * 4]) = b;
            }
        }
        __syncthreads();

        f32x4 accA = {0.f, 0.f, 0.f, 0.f};
        f32x4 accB = {0.f, 0.f, 0.f, 0.f};

        // barrier-free K loop: 16 steps of K=32
        #pragma unroll 4
        for (int ks = 0; ks < 16; ++ks) {
            const int k0 = ks * 32;
            float wf[8];
            #pragma unroll
            for (int i = 0; i < 8; ++i)
                wf[i] = wcol[(size_t)(k0 + 8 * g + i) * OUT];
            bf16x8 bfrag;
            #pragma unroll
            for (int i = 0; i < 8; ++i) bfrag[i] = (short)f2bf(wf[i]);

            const bf16x8 a0 = *reinterpret_cast<const bf16x8*>(
                &Xs[(size_t)ln * XSTR + k0 + 8 * g]);
            accA = __builtin_amdgcn_mfma_f32_16x16x32_bf16(a0, bfrag, accA, 0, 0, 0);
            if (mt_cnt > 1) {
                const bf16x8 a1 = *reinterpret_cast<const bf16x8*>(
                    &Xs[(size_t)(16 + ln) * XSTR + k0 + 8 * g]);
                accB = __builtin_amdgcn_mfma_f32_16x16x32_bf16(a1, bfrag, accB, 0, 0, 0);
            }
        }

        // epilogue: D row=(l>>4)*4+r, col=ln
        #pragma unroll
        for (int mt = 0; mt < 2; ++mt) {
            if (mt == 1 && mt_cnt < 2) break;
            const f32x4 a = (mt == 0) ? accA : accB;
            #pragma unroll
            for (int r = 0; r < 4; ++r) {
                const int slot = mt * 16 + 4 * g + r;
                if (slot < n_c) {
                    const float p = prob_s[slot];
                    const int e = elist[c0 + slot];
                    ysel[(size_t)e * OUT + col] = (a[r] + bcol) * p;
                }
            }
        }
        __syncthreads();   // before restaging next pass
    }
}

// out[t] = ysel[2t] + ysel[2t+1]
__global__ __launch_bounds__(256) void combine(const float* __restrict__ ysel,
                                               float* __restrict__ out) {
    const int i  = blockIdx.x * 256 + threadIdx.x;   // float4 index, 65536
    const int tk = i >> 7;
    const int c  = i & 127;
    const float4* y4 = reinterpret_cast<const float4*>(ysel);
    const size_t b0 = (size_t)(2 * tk) * 128;
    const float4 a = y4[b0 + c];
    const float4 b = y4[b0 + 128 + c];
    float4 r;
    r.x = a.x + b.x; r.y = a.y + b.y; r.z = a.z + b.z; r.w = a.w + b.w;
    reinterpret_cast<float4*>(out)[i] = r;
}

extern "C" void kernel_launch(void* const* d_in, const int* in_sizes, int n_in,
                              void* d_out, int out_size, void* d_ws, size_t ws_size,
                              hipStream_t stream) {
    const float* x     = (const float*)d_in[0];
    const int*   sel   = (const int*)d_in[1];
    const float* probs = (const float*)d_in[2];
    const float* W     = (const float*)d_in[3];
    const float* bias  = (const float*)d_in[4];
    float* out  = (float*)d_out;
    float* ysel = (float*)d_ws;     // [NSEL][OUT] = 2 MB

    banked_mfma<<<NB * 4, 512, 0, stream>>>(x, sel, probs, W, bias, ysel);
    combine<<<(NTOK * OUT / 4) / 256, 256, 0, stream>>>(ysel, out);
}

// Round 12
// 21.036 us; speedup vs baseline: 9.1347x; 1.1124x over previous
//
#include <hip/hip_runtime.h>
#include <stdint.h>

#define NB    64
#define IN    512
#define OUT   512
#define NTOK  512
#define NSEL  1024      // NTOK*K
#define MCAP  32        // token slots per pass (binomial mean 16, sd 4 -> 1 pass)
#define KH    256       // K rows per block (half)
#define XSTR  264       // bf16 per X row (256 + 8 pad; dword-stride 132%32=4)
#define ELCAP 96

typedef __attribute__((ext_vector_type(8))) short bf16x8;
typedef __attribute__((ext_vector_type(4))) float f32x4;

__device__ __forceinline__ ushort f2bf(float f) {   // RNE f32->bf16 (verified R9)
    uint32_t u = __builtin_bit_cast(uint32_t, f);
    u += 0x7fffu + ((u >> 16) & 1u);
    return (ushort)(u >> 16);
}

// Block = (bank, 64-col tile, 256-row K-half): 1024 blocks, 256 thr = 4 waves.
// Wave w = N-tile of 16 cols. MFMA accumulates K=256 (8 steps of 32).
// A (X) staged in LDS bf16 (this half's k-range, ALL 32 slots -- R10/R11 bug
// was staging only slots 0..15 with 256 threads); fragments per m89 layout:
//   A: row=lane&15, k=(lane>>4)*8+i ; B: col=lane&15, same k ;
//   D: col=lane&15, row=(lane>>4)*4+reg.
// B (W) loaded straight from global per-lane scalar (line-disjoint per block),
// packed with the R9-verified integer RNE. K-loop barrier-free. No atomics.
__global__ __launch_bounds__(256) void banked_mfma(
    const float* __restrict__ x,      // [NTOK][IN]
    const int*   __restrict__ sel,    // [NSEL]
    const float* __restrict__ probs,  // [NSEL]
    const float* __restrict__ W,      // [NB][IN][OUT]
    const float* __restrict__ bias,   // [NB][OUT]
    float* __restrict__ ysel)         // [NSEL][2][OUT]
{
    __shared__ __align__(16) ushort Xs[MCAP * XSTR];   // 16.9 KB
    __shared__ int   elist[ELCAP];
    __shared__ int   lcnt;
    __shared__ int   tok_s[MCAP];
    __shared__ float prob_s[MCAP];

    const int bank = blockIdx.x >> 4;
    const int tile = (blockIdx.x >> 1) & 7;   // 64-col tile
    const int half = blockIdx.x & 1;          // K half
    const int t    = threadIdx.x;

    // fused per-bank selection list (slot order free; per-e math invariant)
    if (t == 0) lcnt = 0;
    __syncthreads();
    {
        const int4 s4 = reinterpret_cast<const int4*>(sel)[t];   // t < 256 = NSEL/4
        if (s4.x == bank) { int p = atomicAdd(&lcnt, 1); if (p < ELCAP) elist[p] = 4 * t; }
        if (s4.y == bank) { int p = atomicAdd(&lcnt, 1); if (p < ELCAP) elist[p] = 4 * t + 1; }
        if (s4.z == bank) { int p = atomicAdd(&lcnt, 1); if (p < ELCAP) elist[p] = 4 * t + 2; }
        if (s4.w == bank) { int p = atomicAdd(&lcnt, 1); if (p < ELCAP) elist[p] = 4 * t + 3; }
    }
    __syncthreads();
    const int n = min(lcnt, ELCAP);
    if (n == 0) return;

    const int w   = t >> 6;        // wave = N-tile 0..3
    const int l   = t & 63;
    const int g   = l >> 4;        // lane group 0..3
    const int ln  = l & 15;
    const int col = tile * 64 + w * 16 + ln;
    const int k0b = half * KH;     // this block's K origin
    const float* wcol = W + (size_t)bank * (IN * OUT) + (size_t)k0b * OUT + col;
    const float  bcol = bias[bank * OUT + col];

    for (int c0 = 0; c0 < n; c0 += MCAP) {
        const int n_c    = min(n - c0, MCAP);
        const int mt_cnt = (n_c + 15) >> 4;

        if (t < MCAP) {
            const int idx = c0 + t;
            const int e = (idx < n) ? elist[idx] : 0;
            tok_s[t]  = e >> 1;
            prob_s[t] = (idx < n) ? probs[e] : 0.0f;
        }
        __syncthreads();

        // stage X (this half's k-range) -> LDS bf16 for ALL 32 slots:
        // 32 slots x 64 ushort4 = 2048 stores, 8 per thread
        #pragma unroll
        for (int k2 = 0; k2 < 8; ++k2) {
            const int oid  = t + k2 * 256;
            const int slot = oid >> 6;      // 0..31
            const int f4   = oid & 63;      // 0..63
            const float4 v = reinterpret_cast<const float4*>(
                x + (size_t)tok_s[slot] * IN + k0b)[f4];
            ushort4 b;
            b.x = f2bf(v.x); b.y = f2bf(v.y); b.z = f2bf(v.z); b.w = f2bf(v.w);
            *reinterpret_cast<ushort4*>(&Xs[slot * XSTR + f4 * 4]) = b;
        }
        __syncthreads();

        f32x4 accA = {0.f, 0.f, 0.f, 0.f};
        f32x4 accB = {0.f, 0.f, 0.f, 0.f};

        // barrier-free K loop: 8 steps of K=32
        #pragma unroll 2
        for (int ks = 0; ks < 8; ++ks) {
            const int k0 = ks * 32;
            float wf[8];
            #pragma unroll
            for (int i = 0; i < 8; ++i)
                wf[i] = wcol[(size_t)(k0 + 8 * g + i) * OUT];
            bf16x8 bfrag;
            #pragma unroll
            for (int i = 0; i < 8; ++i) bfrag[i] = (short)f2bf(wf[i]);

            const bf16x8 a0 = *reinterpret_cast<const bf16x8*>(
                &Xs[(size_t)ln * XSTR + k0 + 8 * g]);
            accA = __builtin_amdgcn_mfma_f32_16x16x32_bf16(a0, bfrag, accA, 0, 0, 0);
            if (mt_cnt > 1) {
                const bf16x8 a1 = *reinterpret_cast<const bf16x8*>(
                    &Xs[(size_t)(16 + ln) * XSTR + k0 + 8 * g]);
                accB = __builtin_amdgcn_mfma_f32_16x16x32_bf16(a1, bfrag, accB, 0, 0, 0);
            }
        }

        // epilogue: D row=(l>>4)*4+r, col=ln; bias folded in half 0 only
        #pragma unroll
        for (int mt = 0; mt < 2; ++mt) {
            if (mt == 1 && mt_cnt < 2) break;
            const f32x4 a = (mt == 0) ? accA : accB;
            #pragma unroll
            for (int r = 0; r < 4; ++r) {
                const int slot = mt * 16 + 4 * g + r;
                if (slot < n_c) {
                    const float p = prob_s[slot];
                    const int e = elist[c0 + slot];
                    const float v = (half == 0) ? (a[r] + bcol) * p : a[r] * p;
                    ysel[((size_t)e * 2 + half) * OUT + col] = v;
                }
            }
        }
        __syncthreads();   // before restaging next pass
    }
}

// out[t] = sum over (k=2 selections) x (2 K-halves)
__global__ __launch_bounds__(256) void combine(const float* __restrict__ ysel,
                                               float* __restrict__ out) {
    const int i  = blockIdx.x * 256 + threadIdx.x;   // float4 index, 65536
    const int tk = i >> 7;
    const int c  = i & 127;
    const float4* y4 = reinterpret_cast<const float4*>(ysel);
    const size_t b0 = (size_t)(2 * tk) * 2 * 128;    // [e][half][128 f4]
    const float4 a  = y4[b0 + c];
    const float4 b  = y4[b0 + 128 + c];
    const float4 cc = y4[b0 + 256 + c];
    const float4 d  = y4[b0 + 384 + c];
    float4 r;
    r.x = (a.x + b.x) + (cc.x + d.x);
    r.y = (a.y + b.y) + (cc.y + d.y);
    r.z = (a.z + b.z) + (cc.z + d.z);
    r.w = (a.w + b.w) + (cc.w + d.w);
    reinterpret_cast<float4*>(out)[i] = r;
}

extern "C" void kernel_launch(void* const* d_in, const int* in_sizes, int n_in,
                              void* d_out, int out_size, void* d_ws, size_t ws_size,
                              hipStream_t stream) {
    const float* x     = (const float*)d_in[0];
    const int*   sel   = (const int*)d_in[1];
    const float* probs = (const float*)d_in[2];
    const float* W     = (const float*)d_in[3];
    const float* bias  = (const float*)d_in[4];
    float* out  = (float*)d_out;
    float* ysel = (float*)d_ws;     // [NSEL][2][OUT] = 4 MB

    banked_mfma<<<NB * 8 * 2, 256, 0, stream>>>(x, sel, probs, W, bias, ysel);
    combine<<<(NTOK * OUT / 4) / 256, 256, 0, stream>>>(ysel, out);
}